// Round 3
// baseline (209.330 us; speedup 1.0000x reference)
//
#include <hip/hip_runtime.h>

// Fixed problem shapes
constexpr int B  = 8;
constexpr int C  = 32;
constexpr int H  = 224;
constexpr int Wd = 224;
constexpr int ND = 8;            // num_convs
constexpr int K  = 3;
constexpr int Ho = H - K + 1;    // 222
constexpr int Wo = Wd - K + 1;   // 222
constexpr int JG = (Wo + 3) / 4; // 56 column groups of 4
constexpr int HG = Ho / 2;       // 111 row-pairs (Ho even)
constexpr long PLANE = (long)Ho * Wo;   // 49284 floats
constexpr long DSTR  = (long)C * PLANE; // d-plane stride: 1,577,088 floats

// Native clang vector types (required by __builtin_nontemporal_*)
typedef float vf2 __attribute__((ext_vector_type(2)));
typedef float vf4 __attribute__((ext_vector_type(4)));

__global__ __launch_bounds__(256)
void dconv_kernel(const float* __restrict__ x,
                  const float* __restrict__ Wt,
                  const float* __restrict__ Bv,
                  float* __restrict__ out) {
    int gid = blockIdx.x * blockDim.x + threadIdx.x;
    // gid -> (b, c, ig, jg); jg fastest for coalescing
    int jg = gid % JG;
    int t  = gid / JG;
    int ig = t % HG;
    t     /= HG;
    int c  = t % C;
    int b  = t / C;
    if (b >= B) return;

    const int i0 = ig * 2;   // even output row
    const int j0 = jg * 4;
    const bool edge = (j0 + 4 >= Wd);   // jg == 55: only 2 valid output cols

    // ---- load 4x6 input patch (feeds 2 output rows x 4 cols, all 8 convs) ----
    const float* xp = x + ((long)(b * C + c) * H + i0) * Wd + j0;
    float p[4][6];
#pragma unroll
    for (int r = 0; r < 4; ++r) {
        const vf4 v4 = *reinterpret_cast<const vf4*>(xp + r * Wd);
        p[r][0] = v4.x; p[r][1] = v4.y; p[r][2] = v4.z; p[r][3] = v4.w;
        if (!edge) {
            const vf2 v2 = *reinterpret_cast<const vf2*>(xp + r * Wd + 4);
            p[r][4] = v2.x; p[r][5] = v2.y;
        } else {
            p[r][4] = 0.f;  p[r][5] = 0.f;
        }
    }

    float* ob = out + (long)b * ND * DSTR + (long)c * PLANE + (long)i0 * Wo + j0;

    // ---- all 8 convs from the in-register patch ----
#pragma unroll
    for (int d = 0; d < ND; ++d) {
        float w[9];
#pragma unroll
        for (int q = 0; q < 9; ++q) w[q] = Wt[d * 9 + q];   // uniform -> s_load
        const float bs = Bv[d];

        float a[2][4];
#pragma unroll
        for (int rr = 0; rr < 2; ++rr) {
#pragma unroll
            for (int q = 0; q < 4; ++q) a[rr][q] = bs;
#pragma unroll
            for (int r = 0; r < 3; ++r) {
#pragma unroll
                for (int q = 0; q < 3; ++q) {
                    const float wv = w[r * 3 + q];
                    a[rr][0] = fmaf(wv, p[rr + r][q + 0], a[rr][0]);
                    a[rr][1] = fmaf(wv, p[rr + r][q + 1], a[rr][1]);
                    a[rr][2] = fmaf(wv, p[rr + r][q + 2], a[rr][2]);
                    a[rr][3] = fmaf(wv, p[rr + r][q + 3], a[rr][3]);
                }
            }
        }

        float* op = ob + (long)d * DSTR;
        if (!edge) {
            // even row: offset ≡ 0 mod 16 B -> dense vf4 store
            vf4 s0; s0.x = a[0][0]; s0.y = a[0][1]; s0.z = a[0][2]; s0.w = a[0][3];
            __builtin_nontemporal_store(s0, reinterpret_cast<vf4*>(op));
            // odd row: offset ≡ 8 mod 16 B -> two vf2 stores
            vf2 s1; s1.x = a[1][0]; s1.y = a[1][1];
            vf2 s2; s2.x = a[1][2]; s2.y = a[1][3];
            __builtin_nontemporal_store(s1, reinterpret_cast<vf2*>(op + Wo));
            __builtin_nontemporal_store(s2, reinterpret_cast<vf2*>(op + Wo + 2));
        } else {
            // j0 == 220: only cols 220,221 valid
            vf2 s0; s0.x = a[0][0]; s0.y = a[0][1];
            vf2 s1; s1.x = a[1][0]; s1.y = a[1][1];
            __builtin_nontemporal_store(s0, reinterpret_cast<vf2*>(op));
            __builtin_nontemporal_store(s1, reinterpret_cast<vf2*>(op + Wo));
        }
    }
}

extern "C" void kernel_launch(void* const* d_in, const int* in_sizes, int n_in,
                              void* d_out, int out_size, void* d_ws, size_t ws_size,
                              hipStream_t stream) {
    const float* x  = (const float*)d_in[0];
    const float* Wt = (const float*)d_in[1];   // [1, ND, 3, 3] flat
    const float* Bv = (const float*)d_in[2];   // [ND]
    float* out      = (float*)d_out;           // [B, ND*C, Ho, Wo]

    const int total  = B * C * HG * JG;        // 1,591,296 threads
    const int blocks = (total + 255) / 256;    // 6,216 blocks
    dconv_kernel<<<blocks, 256, 0, stream>>>(x, Wt, Bv, out);
}

// Round 4
// 126.302 us; speedup vs baseline: 1.6574x; 1.6574x over previous
//
#include <hip/hip_runtime.h>

// Fixed problem shapes
constexpr int B  = 8;
constexpr int C  = 32;
constexpr int H  = 224;
constexpr int Wd = 224;
constexpr int ND = 8;            // num_convs
constexpr int K  = 3;
constexpr int Ho = H - K + 1;    // 222
constexpr int Wo = Wd - K + 1;   // 222
constexpr int JG = (Wo + 3) / 4; // 56 column groups of 4
constexpr int HG = Ho / 2;       // 111 row-pairs (Ho even)
constexpr long PLANE = (long)Ho * Wo;   // 49284 floats (plane = 197136 B, ≡0 mod 16)
constexpr long DSTR  = (long)C * PLANE; // d-plane stride

typedef float vf2  __attribute__((ext_vector_type(2)));
typedef float vf4  __attribute__((ext_vector_type(4)));
// float4 store with only 8B alignment guaranteed (odd output rows: row offset
// 888*i ≡ 8 mod 16). AMD global stores need only dword alignment; dense
// 16B/lane at 8-off covers interior 64B lines exactly once.
typedef float vf4u __attribute__((ext_vector_type(4), aligned(8)));

__global__ __launch_bounds__(256)
void dconv_kernel(const float* __restrict__ x,
                  const float* __restrict__ Wt,
                  const float* __restrict__ Bv,
                  float* __restrict__ out) {
    int gid = blockIdx.x * blockDim.x + threadIdx.x;
    // gid -> (b, c, ig, jg); jg fastest for coalescing
    int jg = gid % JG;
    int t  = gid / JG;
    int ig = t % HG;
    t     /= HG;
    int c  = t % C;
    int b  = t / C;
    if (b >= B) return;

    const int i0 = ig * 2;   // even output row
    const int j0 = jg * 4;
    const bool edge = (j0 + 4 >= Wd);   // jg == 55: only 2 valid output cols

    // ---- load 4x6 input patch (feeds 2 output rows x 4 cols, all 8 convs) ----
    const float* xp = x + ((long)(b * C + c) * H + i0) * Wd + j0;
    float p[4][6];
#pragma unroll
    for (int r = 0; r < 4; ++r) {
        const vf4 v4 = *reinterpret_cast<const vf4*>(xp + r * Wd);
        p[r][0] = v4.x; p[r][1] = v4.y; p[r][2] = v4.z; p[r][3] = v4.w;
        if (!edge) {
            const vf2 v2 = *reinterpret_cast<const vf2*>(xp + r * Wd + 4);
            p[r][4] = v2.x; p[r][5] = v2.y;
        } else {
            p[r][4] = 0.f;  p[r][5] = 0.f;
        }
    }

    float* ob = out + (long)b * ND * DSTR + (long)c * PLANE + (long)i0 * Wo + j0;

    // ---- all 8 convs from the in-register patch ----
#pragma unroll
    for (int d = 0; d < ND; ++d) {
        float w[9];
#pragma unroll
        for (int q = 0; q < 9; ++q) w[q] = Wt[d * 9 + q];   // uniform -> s_load
        const float bs = Bv[d];

        float a[2][4];
#pragma unroll
        for (int rr = 0; rr < 2; ++rr) {
#pragma unroll
            for (int q = 0; q < 4; ++q) a[rr][q] = bs;
#pragma unroll
            for (int r = 0; r < 3; ++r) {
#pragma unroll
                for (int q = 0; q < 3; ++q) {
                    const float wv = w[r * 3 + q];
                    a[rr][0] = fmaf(wv, p[rr + r][q + 0], a[rr][0]);
                    a[rr][1] = fmaf(wv, p[rr + r][q + 1], a[rr][1]);
                    a[rr][2] = fmaf(wv, p[rr + r][q + 2], a[rr][2]);
                    a[rr][3] = fmaf(wv, p[rr + r][q + 3], a[rr][3]);
                }
            }
        }

        float* op = ob + (long)d * DSTR;
        if (!edge) {
            // even row: 16B aligned
            vf4 s0; s0.x = a[0][0]; s0.y = a[0][1]; s0.z = a[0][2]; s0.w = a[0][3];
            *reinterpret_cast<vf4*>(op) = s0;
            // odd row: 8 mod 16 — dense float4 store, aligned(8) type
            vf4u s1; s1.x = a[1][0]; s1.y = a[1][1]; s1.z = a[1][2]; s1.w = a[1][3];
            *reinterpret_cast<vf4u*>(op + Wo) = s1;
        } else {
            // j0 == 220: only cols 220,221 valid (both rows 8B aligned)
            vf2 s0; s0.x = a[0][0]; s0.y = a[0][1];
            vf2 s1; s1.x = a[1][0]; s1.y = a[1][1];
            *reinterpret_cast<vf2*>(op) = s0;
            *reinterpret_cast<vf2*>(op + Wo) = s1;
        }
    }
}

extern "C" void kernel_launch(void* const* d_in, const int* in_sizes, int n_in,
                              void* d_out, int out_size, void* d_ws, size_t ws_size,
                              hipStream_t stream) {
    const float* x  = (const float*)d_in[0];
    const float* Wt = (const float*)d_in[1];   // [1, ND, 3, 3] flat
    const float* Bv = (const float*)d_in[2];   // [ND]
    float* out      = (float*)d_out;           // [B, ND*C, Ho, Wo]

    const int total  = B * C * HG * JG;        // 1,591,296 threads
    const int blocks = (total + 255) / 256;    // 6,216 blocks
    dconv_kernel<<<blocks, 256, 0, stream>>>(x, Wt, Bv, out);
}